// Round 8
// baseline (75.271 us; speedup 1.0000x reference)
//
#include <hip/hip_runtime.h>
#include <hip/hip_bf16.h>

#define S_TOT 4096
#define HDIM  1024
#define NH    16
#define DH    64
#define L_    1024
#define NT    19   // 16 local + 3 distinct global tiles (shot-s global == local tile 0, weight 2)

using bf16x8 = __attribute__((ext_vector_type(8))) short;
using f32x16 = __attribute__((ext_vector_type(16))) float;
using i32x4  = __attribute__((ext_vector_type(4))) int;

typedef const __attribute__((address_space(1))) unsigned int* gp1_t;
typedef __attribute__((address_space(3))) unsigned int* lp3_t;

__device__ __forceinline__ short f2bf(float f) {
    union { float f; unsigned u; } x; x.f = f;
    unsigned r = x.u + 0x7FFFu + ((x.u >> 16) & 1u);
    return (short)(r >> 16);
}

__device__ __forceinline__ unsigned cvt_pk_bf16(float lo, float hi) {
    unsigned r;
    asm("v_cvt_pk_bf16_f32 %0, %1, %2" : "=v"(r) : "v"(lo), "v"(hi));
    return r;
}

__device__ __forceinline__ float exp2_fast(float x) {
#if __has_builtin(__builtin_amdgcn_exp2f)
    return __builtin_amdgcn_exp2f(x);
#else
    return exp2f(x);
#endif
}

__device__ __forceinline__ void gload16(const void* g, void* l) {
    __builtin_amdgcn_global_load_lds((gp1_t)g, (lp3_t)(unsigned long)(l), 16, 0, 0);
}

// ---------------- prep: K convert (blocks 0..1023), V transpose (1024..3071) --
__global__ __launch_bounds__(256) void prep_kv(
    const float* __restrict__ kf, const float* __restrict__ vf,
    short* __restrict__ kb, short* __restrict__ vb)
{
    __shared__ short st[64 * 70];
    const int bid = blockIdx.x, tid = threadIdx.x;
    if (bid < 1024) {
        const int gid = bid * 256 + tid;
        #pragma unroll
        for (int it = 0; it < 2; ++it) {
            size_t e = ((size_t)gid + (size_t)it * 262144) * 16;
            #pragma unroll
            for (int half = 0; half < 2; ++half) {
                float4 a = *(const float4*)(kf + e + half * 8);
                float4 c = *(const float4*)(kf + e + half * 8 + 4);
                bf16x8 r;
                r[0]=f2bf(a.x); r[1]=f2bf(a.y); r[2]=f2bf(a.z); r[3]=f2bf(a.w);
                r[4]=f2bf(c.x); r[5]=f2bf(c.y); r[6]=f2bf(c.z); r[7]=f2bf(c.w);
                *(bf16x8*)(kb + e + half * 8) = r;
            }
        }
    } else {
        const int vbid = bid - 1024;
        const int stile = vbid & 63, ht = (vbid >> 6) & 15, b = vbid >> 10;
        const int rt = tid >> 2, q4 = tid & 3;
        const float* src = vf + ((size_t)(b * S_TOT + stile * 64 + rt)) * HDIM + ht * 64 + q4 * 16;
        short* dst = st + rt * 70 + q4 * 16;
        #pragma unroll
        for (int i = 0; i < 4; ++i) {
            float4 x = *(const float4*)(src + i * 4);
            dst[i*4+0] = f2bf(x.x); dst[i*4+1] = f2bf(x.y);
            dst[i*4+2] = f2bf(x.z); dst[i*4+3] = f2bf(x.w);
        }
        __syncthreads();
        const int orow = tid >> 2, oq = tid & 3;
        bf16x8 o0, o1;
        #pragma unroll
        for (int j = 0; j < 8; ++j) o0[j] = st[(oq * 16 + j) * 70 + orow];
        #pragma unroll
        for (int j = 0; j < 8; ++j) o1[j] = st[(oq * 16 + 8 + j) * 70 + orow];
        short* dst2 = vb + ((size_t)((b * NH + ht) * 64 + orow)) * S_TOT + stile * 64 + oq * 16;
        *(bf16x8*)dst2 = o0;
        *(bf16x8*)(dst2 + 8) = o1;
    }
}

// ---------------- attention: R5 dataflow, 2 tiles per barrier pair ----------
// LDS: 4 regions of 16KB (K 8KB | V 8KB each): R0@0 R1@16384 R2@32768 R3@49152.
// Pair j uses regions {R0,R1} if j even, {R2,R3} if j odd (reads); stages the
// NEXT pair into the opposite set. Prologue full-drains (order-robust);
// steady state uses counted vmcnt(8) (= previous iter's 8 loads).
__global__ __launch_bounds__(256, 2) void attn_kernel(
    const float* __restrict__ qf, const short* __restrict__ kb,
    const short* __restrict__ vb, float* __restrict__ out)
{
    __shared__ __align__(16) char smem[65536];
    const int tid  = threadIdx.x;
    const int wave = tid >> 6, lane = tid & 63;
    const int hi   = lane >> 5, q32 = lane & 31;

    // bijective XCD swizzle (512 % 8 == 0)
    const int bidhw = blockIdx.x;
    const int bid = ((bidhw & 7) << 6) | (bidhw >> 3);
    const int qt = bid & 3, h = (bid >> 2) & 15, s = (bid >> 6) & 3, b = bid >> 8;

    // ---- Q B-frags, 2 q-sets of 32 rows (scale*log2e folded in)
    const float CSC = 0.125f * 1.4426950408889634f;
    bf16x8 qv[2][4];
    #pragma unroll
    for (int qs = 0; qs < 2; ++qs) {
        const float* qp = qf + ((size_t)(b*S_TOT + s*L_ + qt*256 + wave*64 + qs*32 + q32)) * HDIM
                             + h * DH + hi * 8;
        #pragma unroll
        for (int d = 0; d < 4; ++d) {
            float4 x0 = *(const float4*)(qp + d * 16);
            float4 x1 = *(const float4*)(qp + d * 16 + 4);
            i32x4 u;
            u[0] = (int)cvt_pk_bf16(x0.x * CSC, x0.y * CSC);
            u[1] = (int)cvt_pk_bf16(x0.z * CSC, x0.w * CSC);
            u[2] = (int)cvt_pk_bf16(x1.x * CSC, x1.y * CSC);
            u[3] = (int)cvt_pk_bf16(x1.z * CSC, x1.w * CSC);
            qv[qs][d] = __builtin_bit_cast(bf16x8, u);
        }
    }

    // ---- staging source offsets (chunk swizzle + K row bit2<->3 permute on the
    // GLOBAL side; LDS dest linear)
    const int cid = tid, row = cid >> 3;
    const int lch = (cid & 7) ^ (row & 7);
    const int krow = (row & 0x33) | ((row & 4) << 1) | ((row & 8) >> 1);
    const size_t ko = (size_t)krow * 2048 + (lch << 4);
    const size_t vo = (size_t)row  * 8192 + (lch << 4);
    const char* kbase = (const char*)kb + ((size_t)b * S_TOT) * 2048 + h * 128;
    const char* vbase = (const char*)vb + ((size_t)(b * NH + h)) * (64ull * 8192);

    auto abs_tile_of = [&](int t) -> int {
        if (t < 16) return s * 16 + t;
        int g = t - 16; if (g >= s) ++g;
        return g * 16;
    };
    auto stage = [&](int t, int rbase) {
        const int at = abs_tile_of(t);
        const char* kp = kbase + (size_t)at * 131072;
        const char* vp = vbase + (size_t)at * 128;
        char* dst = smem + rbase + wave * 1024;
        gload16(kp + ko,          dst);             // K rows  0..31
        gload16(kp + ko + 65536,  dst + 4096);      // K rows 32..63
        gload16(vp + vo,          dst + 8192);      // V^T d 0..31
        gload16(vp + vo + 262144, dst + 12288);     // V^T d 32..63
    };

    // tile-invariant per-lane frag offsets within a region
    int qc[4];
    #pragma unroll
    for (int i = 0; i < 4; ++i)
        qc[i] = q32 * 128 + (((i * 2 + hi) ^ (q32 & 7)) << 4);

    f32x16 zro;
    #pragma unroll
    for (int r = 0; r < 16; ++r) zro[r] = 0.f;
    f32x16 acc[2][2];
    acc[0][0] = zro; acc[0][1] = zro; acc[1][0] = zro; acc[1][1] = zro;
    float ps[2] = {0.f, 0.f};

    // One half-tile chunk: QK (8 mfma) -> softmax -> pack -> PV (8 mfma).
    // RB = region base (runtime), HF = 0/1 (compile-time), W2 = weight-2 flag
    // (compile-time 0/1; tile 0 counted twice via exp2(x+1)).
    #define CHUNK(RB, HF, W2) do {                                                 \
        f32x16 S_[2];                                                              \
        {                                                                          \
            __builtin_amdgcn_s_setprio(1);                                         \
            bf16x8 f0 = *(const bf16x8*)(smem + (RB) + (HF)*4096 + qc[0]);         \
            bf16x8 f1 = *(const bf16x8*)(smem + (RB) + (HF)*4096 + qc[1]);         \
            bf16x8 f2 = *(const bf16x8*)(smem + (RB) + (HF)*4096 + qc[2]);         \
            bf16x8 f3 = *(const bf16x8*)(smem + (RB) + (HF)*4096 + qc[3]);         \
            _Pragma("unroll")                                                      \
            for (int qs = 0; qs < 2; ++qs) {                                       \
                f32x16 a = __builtin_amdgcn_mfma_f32_32x32x16_bf16(f0, qv[qs][0], zro, 0,0,0); \
                a = __builtin_amdgcn_mfma_f32_32x32x16_bf16(f1, qv[qs][1], a, 0,0,0); \
                a = __builtin_amdgcn_mfma_f32_32x32x16_bf16(f2, qv[qs][2], a, 0,0,0); \
                a = __builtin_amdgcn_mfma_f32_32x32x16_bf16(f3, qv[qs][3], a, 0,0,0); \
                S_[qs] = a;                                                        \
            }                                                                      \
            __builtin_amdgcn_s_setprio(0);                                         \
        }                                                                          \
        _Pragma("unroll")                                                          \
        for (int qs = 0; qs < 2; ++qs) {                                           \
            _Pragma("unroll")                                                      \
            for (int r = 0; r < 16; ++r)                                           \
                S_[qs][r] = (W2) ? exp2_fast(S_[qs][r] + 1.0f)                     \
                                 : exp2_fast(S_[qs][r]);                           \
            float s0 = (S_[qs][0] + S_[qs][1]) + (S_[qs][2] + S_[qs][3]);          \
            float s1 = (S_[qs][4] + S_[qs][5]) + (S_[qs][6] + S_[qs][7]);          \
            float s2 = (S_[qs][8] + S_[qs][9]) + (S_[qs][10] + S_[qs][11]);        \
            float s3 = (S_[qs][12] + S_[qs][13]) + (S_[qs][14] + S_[qs][15]);      \
            ps[qs] += (s0 + s1) + (s2 + s3);                                       \
        }                                                                          \
        bf16x8 pf0_[2], pf1_[2];                                                   \
        _Pragma("unroll")                                                          \
        for (int qs = 0; qs < 2; ++qs) {                                           \
            i32x4 u;                                                               \
            u[0] = (int)cvt_pk_bf16(S_[qs][0],  S_[qs][1]);                        \
            u[1] = (int)cvt_pk_bf16(S_[qs][2],  S_[qs][3]);                        \
            u[2] = (int)cvt_pk_bf16(S_[qs][4],  S_[qs][5]);                        \
            u[3] = (int)cvt_pk_bf16(S_[qs][6],  S_[qs][7]);                        \
            pf0_[qs] = __builtin_bit_cast(bf16x8, u);                              \
            u[0] = (int)cvt_pk_bf16(S_[qs][8],  S_[qs][9]);                        \
            u[1] = (int)cvt_pk_bf16(S_[qs][10], S_[qs][11]);                       \
            u[2] = (int)cvt_pk_bf16(S_[qs][12], S_[qs][13]);                       \
            u[3] = (int)cvt_pk_bf16(S_[qs][14], S_[qs][15]);                       \
            pf1_[qs] = __builtin_bit_cast(bf16x8, u);                              \
        }                                                                          \
        {                                                                          \
            __builtin_amdgcn_s_setprio(1);                                         \
            bf16x8 w00 = *(const bf16x8*)(smem + (RB) + 8192  + qc[2*(HF)]);       \
            bf16x8 w01 = *(const bf16x8*)(smem + (RB) + 8192  + qc[2*(HF)+1]);     \
            bf16x8 w10 = *(const bf16x8*)(smem + (RB) + 12288 + qc[2*(HF)]);       \
            bf16x8 w11 = *(const bf16x8*)(smem + (RB) + 12288 + qc[2*(HF)+1]);     \
            _Pragma("unroll")                                                      \
            for (int qs = 0; qs < 2; ++qs) {                                       \
                acc[qs][0] = __builtin_amdgcn_mfma_f32_32x32x16_bf16(w00, pf0_[qs], acc[qs][0], 0,0,0); \
                acc[qs][0] = __builtin_amdgcn_mfma_f32_32x32x16_bf16(w01, pf1_[qs], acc[qs][0], 0,0,0); \
                acc[qs][1] = __builtin_amdgcn_mfma_f32_32x32x16_bf16(w10, pf0_[qs], acc[qs][1], 0,0,0); \
                acc[qs][1] = __builtin_amdgcn_mfma_f32_32x32x16_bf16(w11, pf1_[qs], acc[qs][1], 0,0,0); \
            }                                                                      \
            __builtin_amdgcn_s_setprio(0);                                         \
        }                                                                          \
    } while (0)

    #define BARRIER() do {                                                         \
        __builtin_amdgcn_sched_barrier(0);                                         \
        __builtin_amdgcn_s_barrier();                                              \
        __builtin_amdgcn_sched_barrier(0);                                         \
    } while (0)

    // ---- prologue: tiles {0,1} -> R0,R1; full drain (order-robust)
    stage(0, 0);
    stage(1, 16384);
    asm volatile("s_waitcnt vmcnt(0)" ::: "memory");
    BARRIER();

    // ---- peeled pair j=0: stage {2,3}->R2,R3; compute tiles 0 (w2),1
    stage(2, 32768);
    stage(3, 49152);
    asm volatile("s_waitcnt vmcnt(8)" ::: "memory");   // no-op; {0,1} drained
    BARRIER();
    CHUNK(0, 0, 1); CHUNK(0, 1, 1);          // tile 0, weight 2
    CHUNK(16384, 0, 0); CHUNK(16384, 1, 0);  // tile 1
    BARRIER();

    // ---- main loop: pairs j=1..8 (tiles {2j,2j+1}); stage pair j+1
    for (int j = 1; j < 9; ++j) {
        const int rS = (j & 1) ? 0 : 32768;         // stage dest (pair j+1)
        const int rC = (j & 1) ? 32768 : 0;         // compute src (pair j)
        int ts0 = 2*j + 2, ts1 = 2*j + 3;
        if (ts0 > 18) ts0 = 18;
        if (ts1 > 18) ts1 = 18;
        stage(ts0, rS);
        stage(ts1, rS + 16384);
        asm volatile("s_waitcnt vmcnt(8)" ::: "memory");  // prev iter's 8 done
        BARRIER();
        CHUNK(rC, 0, 0); CHUNK(rC, 1, 0);                 // tile 2j
        CHUNK(rC + 16384, 0, 0); CHUNK(rC + 16384, 1, 0); // tile 2j+1
        BARRIER();
    }

    // ---- epilogue: tile 18 (staged at j=8 into R2; R3 holds unused dup)
    asm volatile("s_waitcnt vmcnt(0)" ::: "memory");
    BARRIER();
    CHUNK(32768, 0, 0); CHUNK(32768, 1, 0);

    // ---- denominators + store
    #pragma unroll
    for (int qs = 0; qs < 2; ++qs) {
        float tot = ps[qs] + __shfl_xor(ps[qs], 32);
        float inv = 1.0f / tot;
        const size_t orow = (size_t)(b*S_TOT + s*L_ + qt*256 + wave*64 + qs*32 + q32);
        float* op = out + orow * HDIM + h * DH;
        #pragma unroll
        for (int m = 0; m < 4; ++m) {
            float4 w0, w1;
            w0.x = acc[qs][0][4*m+0]*inv; w0.y = acc[qs][0][4*m+1]*inv;
            w0.z = acc[qs][0][4*m+2]*inv; w0.w = acc[qs][0][4*m+3]*inv;
            *(float4*)(op + 8*m + 4*hi) = w0;
            w1.x = acc[qs][1][4*m+0]*inv; w1.y = acc[qs][1][4*m+1]*inv;
            w1.z = acc[qs][1][4*m+2]*inv; w1.w = acc[qs][1][4*m+3]*inv;
            *(float4*)(op + 32 + 8*m + 4*hi) = w1;
        }
    }
}

extern "C" void kernel_launch(void* const* d_in, const int* in_sizes, int n_in,
                              void* d_out, int out_size, void* d_ws, size_t ws_size,
                              hipStream_t stream) {
    const float* q = (const float*)d_in[0];
    const float* k = (const float*)d_in[1];
    const float* v = (const float*)d_in[2];
    char* ws = (char*)d_ws;
    short* kbuf = (short*)(ws);
    short* vbuf = (short*)(ws + (16u << 20));
    prep_kv<<<dim3(3072), dim3(256), 0, stream>>>(k, v, kbuf, vbuf);
    attn_kernel<<<dim3(512), dim3(256), 0, stream>>>(q, kbuf, vbuf, (float*)d_out);
}